// Round 1
// baseline (59.122 us; speedup 1.0000x reference)
//
#include <hip/hip_runtime.h>

// ChamferDistance: B=4, N=M=8192, fp32 3-D points.
// dist1[b,i] = min_j ||x_i - y_j||^2 ; dist2[b,j] = min_i ||x_i - y_j||^2
// Strategy: expansion form d = n1 + (n2 - 2 x.y). Per thread: KX owned points
// with x' = -2x and n1 in regs; loop over a 512-point LDS-staged tile of the
// other cloud (float4 = y0,y1,y2,n2). Inner body = 3 fma + 1 min per pair.
// min_y d = n1 + min_y t  -> n1 applied once at the end, clamped at 0.
// y-loop split into 16 chunks across blocks for occupancy; chunk partials
// combined with int-punned atomicMin (valid for non-negative IEEE floats).

#define B_      4
#define N_      8192
#define M_      8192
#define THREADS 256
#define KX      2
#define TY      512

__global__ __launch_bounds__(THREADS)
void cd_init(float* __restrict__ out, int n) {
    int i = blockIdx.x * THREADS + threadIdx.x;
    if (i < n) out[i] = __int_as_float(0x7f800000);  // +inf
}

__global__ __launch_bounds__(THREADS)
void cd_pass(const float* __restrict__ xs,   // owning cloud  (B, Nx, 3)
             const float* __restrict__ ys,   // scanned cloud (B, My, 3)
             float* __restrict__ out,        // (B, Nx) partial-min via atomic
             int Nx, int My, int nxblk, int nchunk) {
    __shared__ float  raw[TY * 3];
    __shared__ float4 ysh[TY];

    int bid = blockIdx.x;
    int c   = bid % nchunk;  bid /= nchunk;
    int xb  = bid % nxblk;
    int b   = bid / nxblk;

    // Stage TY scanned points: raw float3 -> LDS -> repack float4 with n2 in .w
    const float4* ybase4 = (const float4*)(ys + ((size_t)b * My + (size_t)c * TY) * 3);
    for (int t = threadIdx.x; t < TY * 3 / 4; t += THREADS)
        ((float4*)raw)[t] = ybase4[t];
    __syncthreads();
    for (int t = threadIdx.x; t < TY; t += THREADS) {
        float a0 = raw[3*t], a1 = raw[3*t+1], a2 = raw[3*t+2];
        ysh[t] = make_float4(a0, a1, a2, a0*a0 + a1*a1 + a2*a2);
    }
    __syncthreads();

    // Owned points: x' = -2x, n1, running t-min
    float xp0[KX], xp1[KX], xp2[KX], n1[KX], tmin[KX];
    int   xi[KX];
    #pragma unroll
    for (int k = 0; k < KX; ++k) {
        xi[k] = xb * (THREADS * KX) + k * THREADS + threadIdx.x;
        size_t base = ((size_t)b * Nx + xi[k]) * 3;
        float a0 = xs[base], a1 = xs[base + 1], a2 = xs[base + 2];
        n1[k]  = a0*a0 + a1*a1 + a2*a2;
        xp0[k] = -2.f * a0;
        xp1[k] = -2.f * a1;
        xp2[k] = -2.f * a2;
        tmin[k] = __int_as_float(0x7f800000);
    }

    // Inner loop: 1 broadcast ds_read_b128 + KX*(3 fma + 1 min) per scanned pt
    #pragma unroll 8
    for (int j = 0; j < TY; ++j) {
        float4 y = ysh[j];
        #pragma unroll
        for (int k = 0; k < KX; ++k) {
            float t = fmaf(xp0[k], y.x, fmaf(xp1[k], y.y, fmaf(xp2[k], y.z, y.w)));
            tmin[k] = fminf(tmin[k], t);
        }
    }

    #pragma unroll
    for (int k = 0; k < KX; ++k) {
        float v = fmaxf(n1[k] + tmin[k], 0.f);
        // positive IEEE floats order-preserve as signed ints
        atomicMin((int*)&out[(size_t)b * Nx + xi[k]], __float_as_int(v));
    }
}

extern "C" void kernel_launch(void* const* d_in, const int* in_sizes, int n_in,
                              void* d_out, int out_size, void* d_ws, size_t ws_size,
                              hipStream_t stream) {
    const float* xyz1 = (const float*)d_in[0];
    const float* xyz2 = (const float*)d_in[1];
    float* out = (float*)d_out;

    cd_init<<<(out_size + THREADS - 1) / THREADS, THREADS, 0, stream>>>(out, out_size);

    const int nxblk1 = N_ / (THREADS * KX);  // 16
    const int nch1   = M_ / TY;              // 16
    cd_pass<<<B_ * nxblk1 * nch1, THREADS, 0, stream>>>(
        xyz1, xyz2, out, N_, M_, nxblk1, nch1);

    const int nxblk2 = M_ / (THREADS * KX);
    const int nch2   = N_ / TY;
    cd_pass<<<B_ * nxblk2 * nch2, THREADS, 0, stream>>>(
        xyz2, xyz1, out + (size_t)B_ * N_, M_, N_, nxblk2, nch2);
}

// Round 2
// 56.753 us; speedup vs baseline: 1.0417x; 1.0417x over previous
//
#include <hip/hip_runtime.h>

// ChamferDistance: B=4, N=M=8192, fp32 3-D points.
// d = n1 + (n2 - 2 x.y);  min over scanned cloud; clamp >= 0.
// Round 2: KX=8 owned points/thread (1 uniform ds_read_b128 : 32 VALU),
// pre-packed float4 (x,y,z,n2) clouds in d_ws, init fused into pack kernel,
// chunked y-loop combined via int-punned atomicMin (exact for min).

#define B_      4
#define N_      8192
#define M_      8192
#define THREADS 256
#define KX      8          // owned points per thread
#define TY      256        // scanned points staged per block
#define NCHUNK  32         // y-chunks per (b, xb)
#define NXBLK   (N_ / (THREADS * KX))   // 4
#define PINF    __int_as_float(0x7f800000)

__global__ __launch_bounds__(THREADS)
void cd_pack_init(const float* __restrict__ xyz1, const float* __restrict__ xyz2,
                  float4* __restrict__ p1, float4* __restrict__ p2,
                  float* __restrict__ out) {
    int i = blockIdx.x * THREADS + threadIdx.x;
    if (i < B_ * N_) {
        float a0 = xyz1[3*i], a1 = xyz1[3*i+1], a2 = xyz1[3*i+2];
        p1[i] = make_float4(a0, a1, a2, a0*a0 + a1*a1 + a2*a2);
    }
    if (i < B_ * M_) {
        float a0 = xyz2[3*i], a1 = xyz2[3*i+1], a2 = xyz2[3*i+2];
        p2[i] = make_float4(a0, a1, a2, a0*a0 + a1*a1 + a2*a2);
    }
    if (i < B_ * (N_ + M_)) out[i] = PINF;   // out_size = B*(N+M)
}

__global__ __launch_bounds__(THREADS)
void cd_pass(const float4* __restrict__ xs,   // packed owning cloud  (B, 8192)
             const float4* __restrict__ ys,   // packed scanned cloud (B, 8192)
             float* __restrict__ out) {       // (B, 8192) partial-min via atomic
    __shared__ float4 ysh[TY];

    int bid = blockIdx.x;
    int c   = bid & (NCHUNK - 1);  bid >>= 5;     // NCHUNK = 32
    int xb  = bid & (NXBLK - 1);   bid >>= 2;     // NXBLK  = 4
    int b   = bid;

    // Stage TY scanned float4 points (coalesced, once per block)
    ysh[threadIdx.x] = ys[(size_t)b * M_ + c * TY + threadIdx.x];

    // Owned points: x' = -2x in regs, n1 deferred to epilogue
    float xp0[KX], xp1[KX], xp2[KX], nx[KX], tmin[KX];
    const int xbase = xb * (THREADS * KX);
    #pragma unroll
    for (int k = 0; k < KX; ++k) {
        float4 x = xs[(size_t)b * N_ + xbase + k * THREADS + threadIdx.x];
        xp0[k] = -2.f * x.x;
        xp1[k] = -2.f * x.y;
        xp2[k] = -2.f * x.z;
        nx[k]  = x.w;
        tmin[k] = PINF;
    }
    __syncthreads();

    // Inner loop: 1 broadcast ds_read_b128 : KX*(3 fma + 1 min)
    #pragma unroll 4
    for (int j = 0; j < TY; ++j) {
        float4 y = ysh[j];
        #pragma unroll
        for (int k = 0; k < KX; ++k) {
            float t = fmaf(xp0[k], y.x, fmaf(xp1[k], y.y, fmaf(xp2[k], y.z, y.w)));
            tmin[k] = fminf(tmin[k], t);
        }
    }

    #pragma unroll
    for (int k = 0; k < KX; ++k) {
        float v = fmaxf(nx[k] + tmin[k], 0.f);
        // non-negative IEEE floats order-preserve as signed ints
        atomicMin((int*)&out[(size_t)b * N_ + xbase + k * THREADS + threadIdx.x],
                  __float_as_int(v));
    }
}

extern "C" void kernel_launch(void* const* d_in, const int* in_sizes, int n_in,
                              void* d_out, int out_size, void* d_ws, size_t ws_size,
                              hipStream_t stream) {
    const float* xyz1 = (const float*)d_in[0];
    const float* xyz2 = (const float*)d_in[1];
    float* out = (float*)d_out;

    float4* p1 = (float4*)d_ws;              // B*N float4
    float4* p2 = p1 + (size_t)B_ * N_;       // B*M float4  (1 MB total, ws is ~256 MB)

    cd_pack_init<<<(B_ * (N_ + M_) + THREADS - 1) / THREADS, THREADS, 0, stream>>>(
        xyz1, xyz2, p1, p2, out);

    const int grid = B_ * NXBLK * NCHUNK;    // 512 blocks = 2/CU
    cd_pass<<<grid, THREADS, 0, stream>>>(p1, p2, out);                      // dist1
    cd_pass<<<grid, THREADS, 0, stream>>>(p2, p1, out + (size_t)B_ * N_);    // dist2
}

// Round 3
// 52.322 us; speedup vs baseline: 1.1300x; 1.0847x over previous
//
#include <hip/hip_runtime.h>

// ChamferDistance: B=4, N=M=8192, fp32 3-D points.
// d = n1 + (n2 - 2 x.y);  min over scanned cloud; clamp >= 0.
// R3: both directions merged into ONE kernel (grid 1024 = 4 blocks/CU =
// 4 waves/SIMD for latency hiding), KX=8 owned pts/thread, unroll 8.
// Packed float4 (x,y,z,n2) clouds in d_ws; out init fused into pack kernel;
// chunk partials combined via int-punned atomicMin (exact, non-neg floats).

#define B_      4
#define N_      8192
#define M_      8192
#define THREADS 256
#define KX      8                       // owned points per thread
#define TY      256                     // scanned points staged per block
#define NCHUNK  32                      // y-chunks per (b, xb)
#define NXBLK   (N_ / (THREADS * KX))   // 4
#define PINF    __int_as_float(0x7f800000)

__global__ __launch_bounds__(THREADS)
void cd_pack_init(const float* __restrict__ xyz1, const float* __restrict__ xyz2,
                  float4* __restrict__ p1, float4* __restrict__ p2,
                  float* __restrict__ out) {
    int i = blockIdx.x * THREADS + threadIdx.x;
    if (i < B_ * N_) {
        float a0 = xyz1[3*i], a1 = xyz1[3*i+1], a2 = xyz1[3*i+2];
        p1[i] = make_float4(a0, a1, a2, a0*a0 + a1*a1 + a2*a2);
    }
    if (i < B_ * M_) {
        float a0 = xyz2[3*i], a1 = xyz2[3*i+1], a2 = xyz2[3*i+2];
        p2[i] = make_float4(a0, a1, a2, a0*a0 + a1*a1 + a2*a2);
    }
    if (i < B_ * (N_ + M_)) out[i] = PINF;   // out_size = B*(N+M)
}

__global__ __launch_bounds__(THREADS, 4)   // cap 128 VGPR -> 4 blocks/CU
void cd_pass(const float4* __restrict__ p1,
             const float4* __restrict__ p2,
             float* __restrict__ out) {
    __shared__ float4 ysh[TY];

    int bid  = blockIdx.x;
    int c    = bid & (NCHUNK - 1);  bid >>= 5;
    int xb   = bid & (NXBLK - 1);   bid >>= 2;
    int b    = bid & (B_ - 1);      bid >>= 2;
    int pass = bid;                                   // 0: dist1, 1: dist2

    const float4* xs = pass ? p2 : p1;
    const float4* ys = pass ? p1 : p2;
    float* o = out + (pass ? (size_t)B_ * N_ : 0);

    // Stage TY scanned float4 points (coalesced, once per block)
    ysh[threadIdx.x] = ys[(size_t)b * M_ + c * TY + threadIdx.x];

    // Owned points: x' = -2x in regs; n1 deferred to epilogue
    float xp0[KX], xp1[KX], xp2[KX], nx[KX], tmin[KX];
    const int xbase = xb * (THREADS * KX);
    #pragma unroll
    for (int k = 0; k < KX; ++k) {
        float4 x = xs[(size_t)b * N_ + xbase + k * THREADS + threadIdx.x];
        xp0[k] = -2.f * x.x;
        xp1[k] = -2.f * x.y;
        xp2[k] = -2.f * x.z;
        nx[k]  = x.w;
        tmin[k] = PINF;
    }
    __syncthreads();

    // Inner loop: 1 broadcast ds_read_b128 : KX*(3 fma + 1 min)
    #pragma unroll 8
    for (int j = 0; j < TY; ++j) {
        float4 y = ysh[j];
        #pragma unroll
        for (int k = 0; k < KX; ++k) {
            float t = fmaf(xp0[k], y.x, fmaf(xp1[k], y.y, fmaf(xp2[k], y.z, y.w)));
            tmin[k] = fminf(tmin[k], t);
        }
    }

    #pragma unroll
    for (int k = 0; k < KX; ++k) {
        float v = fmaxf(nx[k] + tmin[k], 0.f);
        // non-negative IEEE floats order-preserve as signed ints
        atomicMin((int*)&o[(size_t)b * N_ + xbase + k * THREADS + threadIdx.x],
                  __float_as_int(v));
    }
}

extern "C" void kernel_launch(void* const* d_in, const int* in_sizes, int n_in,
                              void* d_out, int out_size, void* d_ws, size_t ws_size,
                              hipStream_t stream) {
    const float* xyz1 = (const float*)d_in[0];
    const float* xyz2 = (const float*)d_in[1];
    float* out = (float*)d_out;

    float4* p1 = (float4*)d_ws;              // B*N float4
    float4* p2 = p1 + (size_t)B_ * N_;       // B*M float4  (1 MB total)

    cd_pack_init<<<(B_ * (N_ + M_) + THREADS - 1) / THREADS, THREADS, 0, stream>>>(
        xyz1, xyz2, p1, p2, out);

    // both directions in one launch: 2 * B * NXBLK * NCHUNK = 1024 blocks
    cd_pass<<<2 * B_ * NXBLK * NCHUNK, THREADS, 0, stream>>>(p1, p2, out);
}